// Round 11
// baseline (28.921 us; speedup 1.0000x reference)
//
#include <hip/hip_runtime.h>

// Shapes fixed by reference setup_inputs(): (B=16, NI=11, T=65536), LST=64.
#define B_   16
#define NI   11
#define T_   65536
#define LST  64
#define NBLK (T_ / LST)     // 1024
#define ROWP 68             // LDS row stride (floats): 272B, 16B-aligned

#define DPP_XOR1 0xB1       // quad_perm(1,0,3,2)  == xor lane^1
#define DPP_XOR2 0x4E       // quad_perm(2,3,0,1)  == xor lane^2

__device__ __forceinline__ float frcp(float x) { return __builtin_amdgcn_rcpf(x); }

template<int CTRL>
__device__ __forceinline__ float dppf(float x) {
    return __int_as_float(__builtin_amdgcn_update_dpp(
        0, __float_as_int(x), CTRL, 0xF, 0xF, true));
}
template<int CTRL>
__device__ __forceinline__ int dppi(int x) {
    return __builtin_amdgcn_update_dpp(0, x, CTRL, 0xF, 0xF, true);
}

__device__ __forceinline__ void ce_desc(float& a, float& b) {
    float mx = fmaxf(a, b);
    float mn = fminf(a, b);
    a = mx; b = mn;
}

// One wave per (b, jb) tile of 11 instruments x 64 timesteps. Fully fused.
// Layout change vs R10: lane (g,q) loads its row-chunk (16 floats of row g)
// DIRECTLY from global (4x dwordx4, 64B/lane coalesced) -> time solve needs
// no LDS round trip. LDS staging (4x b128/lane) only feeds the column
// (instrument) solve and the 5 duplicate groups.
// - time tau: Michelot warm-started at tau0 = max(M1-1, (sum4 lanemaxes-1)/4).
//   Any k distinct elements give (sum-1)/k <= tau* (prefix-max theorem), so
//   tau0 <= tau* and Michelot stays monotone; count-stable stop == exact KKT.
//   Gaussian data: support(tau0) ~3.4 -> ~3.5 iters (was ~6 from max-1).
// - instrument tau (d=11): branch-free sort-network + one masked prefix pass.
__global__ __launch_bounds__(256) void fused_sparsemax_kernel(
        const float* __restrict__ in, float* __restrict__ out) {
    __shared__ float ldsz[4][NI * ROWP];   // z tile, row-major [inst][t]
    __shared__ float ldsti[4][64];         // tau_inst[t] transpose buffer

    const int lane = threadIdx.x & 63;
    const int wid  = threadIdx.x >> 6;
    const int tile = blockIdx.x * 4 + wid;          // 16384 tiles
    const int b    = tile >> 10;
    const int jb   = tile & (NBLK - 1);

    const int g     = lane >> 2;
    const int q     = lane & 3;
    const bool realg = (g < NI);
    const int  row   = realg ? g : (g - NI);        // spare groups duplicate

    const size_t rbase = (size_t)b * NI * T_ + (size_t)row * T_
                       + (size_t)jb * LST + (size_t)q * 16;

    // ---- row-major load: 4x float4 per lane (groups 0..10 only) ----
    float y[16];
    if (realg) {
        const float4* p4 = reinterpret_cast<const float4*>(in + rbase);
        float4 v0 = p4[0], v1 = p4[1], v2 = p4[2], v3 = p4[3];
        y[0]=v0.x;  y[1]=v0.y;  y[2]=v0.z;  y[3]=v0.w;
        y[4]=v1.x;  y[5]=v1.y;  y[6]=v1.z;  y[7]=v1.w;
        y[8]=v2.x;  y[9]=v2.y;  y[10]=v2.z; y[11]=v2.w;
        y[12]=v3.x; y[13]=v3.y; y[14]=v3.z; y[15]=v3.w;
        // stage for the column solve + duplicate groups (4x ds_write_b128)
        float4* w = reinterpret_cast<float4*>(&ldsz[wid][g * ROWP + q * 16]);
        w[0]=v0; w[1]=v1; w[2]=v2; w[3]=v3;
    } else {
        // duplicate groups pull rows 0..4 back from LDS (wave-local order)
        const float4* rr = reinterpret_cast<const float4*>(
            &ldsz[wid][row * ROWP + q * 16]);
        float4 v0 = rr[0], v1 = rr[1], v2 = rr[2], v3 = rr[3];
        y[0]=v0.x;  y[1]=v0.y;  y[2]=v0.z;  y[3]=v0.w;
        y[4]=v1.x;  y[5]=v1.y;  y[6]=v1.z;  y[7]=v1.w;
        y[8]=v2.x;  y[9]=v2.y;  y[10]=v2.z; y[11]=v2.w;
        y[12]=v3.x; y[13]=v3.y; y[14]=v3.z; y[15]=v3.w;
    }

    // ---- instrument tau: per-lane column solve (lane == t) ----
    float s[NI];
#pragma unroll
    for (int i = 0; i < NI; ++i) s[i] = ldsz[wid][i * ROWP + lane];
#pragma unroll
    for (int p = 0; p < NI; ++p) {                  // OETS-11: 55 CE
#pragma unroll
        for (int k = (p & 1); k + 1 < NI; k += 2) ce_desc(s[k], s[k + 1]);
    }
    float cum = 0.0f, tsum = 0.0f;
    int   kz  = 0;
#pragma unroll
    for (int k = 1; k <= NI; ++k) {
        cum += s[k - 1];
        bool cond = fmaf((float)k, s[k - 1], 1.0f) > cum;  // 1 + k*s_k > cum_k
        kz   += cond ? 1 : 0;                       // support size (prefix)
        tsum += cond ? s[k - 1] : 0.0f;             // == cumsum[k_z - 1]
    }
    ldsti[wid][lane] = (tsum - 1.0f) * frcp((float)kz);

    // ---- time tau: warm-started Michelot, count-stable == exact ----
    float lm = y[0];
#pragma unroll
    for (int r = 1; r < 16; ++r) lm = fmaxf(lm, y[r]);   // per-lane max
    float M1 = fmaxf(lm, dppf<DPP_XOR1>(lm));
    M1 = fmaxf(M1, dppf<DPP_XOR2>(M1));                  // group max
    float S4 = lm + dppf<DPP_XOR1>(lm);
    S4 += dppf<DPP_XOR2>(S4);                            // sum of 4 lane-maxes
    float tau = fmaxf(M1 - 1.0f, (S4 - 1.0f) * 0.25f);   // both <= tau*

    int prev = 0;
    for (int it = 0; it < LST + 2; ++it) {
        float ss = 0.0f;
        int   cc = 0;
#pragma unroll
        for (int r = 0; r < 16; ++r) {
            bool a = y[r] > tau;
            ss += a ? y[r] : 0.0f;
            cc += a ? 1 : 0;
        }
        ss += dppf<DPP_XOR1>(ss);
        ss += dppf<DPP_XOR2>(ss);
        cc += dppi<DPP_XOR1>(cc);
        cc += dppi<DPP_XOR2>(cc);
        if (!__any(cc != prev)) break;              // stable set -> exact
        prev = cc;
        tau  = (ss - 1.0f) * frcp((float)cc);
    }

    // ---- epilogue: out = relu(y - tau_time) * relu(y - tau_inst) ----
    if (realg) {
        float ti[16];                               // 4x ds_read_b128
#pragma unroll
        for (int r = 0; r < 16; ++r) ti[r] = ldsti[wid][q * 16 + r];

        float4* po4 = reinterpret_cast<float4*>(out + rbase);
#pragma unroll
        for (int v = 0; v < 4; ++v) {
            float4 o;
            o.x = fmaxf(y[4*v+0] - tau, 0.0f) * fmaxf(y[4*v+0] - ti[4*v+0], 0.0f);
            o.y = fmaxf(y[4*v+1] - tau, 0.0f) * fmaxf(y[4*v+1] - ti[4*v+1], 0.0f);
            o.z = fmaxf(y[4*v+2] - tau, 0.0f) * fmaxf(y[4*v+2] - ti[4*v+2], 0.0f);
            o.w = fmaxf(y[4*v+3] - tau, 0.0f) * fmaxf(y[4*v+3] - ti[4*v+3], 0.0f);
            po4[v] = o;
        }
    }
}

extern "C" void kernel_launch(void* const* d_in, const int* in_sizes, int n_in,
                              void* d_out, int out_size, void* d_ws, size_t ws_size,
                              hipStream_t stream) {
    const float* in = (const float*)d_in[0];
    float* out = (float*)d_out;
    // 16384 wave-tiles, 4 waves per 256-thread block -> 4096 blocks
    hipLaunchKernelGGL(fused_sparsemax_kernel, dim3(4096), dim3(256), 0, stream,
                       in, out);
}